// Round 1
// baseline (257.906 us; speedup 1.0000x reference)
//
#include <hip/hip_runtime.h>

// Decay-based linear recurrent scan (RetNet-style):
//   S_t = d * S_{t-1} + (1-d) * kv_t ;  out_t = q_t * S_t
// Shapes: q,kv,out (T,B,H,V,D) fp32; decay (1,1,H,1,D) fp32.
// T=128, B=16, H=8, V=25, D=64 -> 204800 independent scalar recurrences.
// One thread per channel; T-loop with coalesced stride-CH accesses.

#define T_DIM 128
#define B_DIM 16
#define H_DIM 8
#define V_DIM 25
#define D_DIM 64
#define CH (B_DIM * H_DIM * V_DIM * D_DIM)  // 204800

__global__ __launch_bounds__(256) void sss_scan_kernel(
    const float* __restrict__ q,
    const float* __restrict__ kv,
    const float* __restrict__ decay,
    float* __restrict__ out)
{
    const int i = blockIdx.x * blockDim.x + threadIdx.x;
    if (i >= CH) return;

    // channel -> (h, dd) for decay lookup: i = ((b*H + h)*V + v)*D + dd
    const int dd = i & (D_DIM - 1);
    const int h  = (i / (V_DIM * D_DIM)) % H_DIM;
    const float d   = decay[h * D_DIM + dd];
    const float omd = 1.0f - d;

    const float* __restrict__ qp = q  + i;
    const float* __restrict__ kp = kv + i;
    float*       __restrict__ op = out + i;

    float S = 0.0f;
    #pragma unroll 4
    for (int t = 0; t < T_DIM; ++t) {
        const size_t off = (size_t)t * CH;
        const float kvt = kp[off];
        const float qt  = qp[off];
        S = fmaf(d, S, omd * kvt);
        op[off] = qt * S;
    }
}

extern "C" void kernel_launch(void* const* d_in, const int* in_sizes, int n_in,
                              void* d_out, int out_size, void* d_ws, size_t ws_size,
                              hipStream_t stream) {
    const float* q     = (const float*)d_in[0];
    const float* kv    = (const float*)d_in[1];
    const float* decay = (const float*)d_in[2];
    float* out = (float*)d_out;

    const int threads = 256;
    const int blocks  = (CH + threads - 1) / threads;  // 800
    sss_scan_kernel<<<blocks, threads, 0, stream>>>(q, kv, decay, out);
}

// Round 2
// 256.195 us; speedup vs baseline: 1.0067x; 1.0067x over previous
//
#include <hip/hip_runtime.h>

// Decay-based linear recurrent scan:  S_t = d*S_{t-1} + (1-d)*kv_t ; out_t = q_t*S_t
// fp32, (T,B,H,V,D) = (128,16,8,25,64). 204800 independent channels.
// Round-2 design: float4 per lane (16B loads), 64-thread blocks (800 blocks -> all CUs),
// explicit group-of-4 double-buffered prefetch => 8 global_load_dwordx4 in flight/wave.
// Latency-bound fix: 3.1 waves/CU * 8 KB in flight = 25 KB/CU > 9.2 KB needed for 6.3 TB/s.

#define T_DIM 128
#define CH   204800          // B*H*V*D
#define CH4  (CH / 4)        // 51200 float4 channels
#define VD   (25 * 64)       // V*D

__global__ __launch_bounds__(64) void sss_scan_v4(
    const float4* __restrict__ q,
    const float4* __restrict__ kv,
    const float*  __restrict__ decay,
    float4* __restrict__ out)
{
    const int i  = blockIdx.x * 64 + threadIdx.x;   // float4-channel index
    const int e0 = i * 4;                           // scalar element base
    const int dd = e0 & 63;                         // d-offset (multiple of 4)
    const int h  = (e0 / VD) & 7;                   // head index

    const float4 d   = *(const float4*)(decay + h * 64 + dd);
    const float4 omd = make_float4(1.0f - d.x, 1.0f - d.y, 1.0f - d.z, 1.0f - d.w);

    const float4* __restrict__ qp = q  + i;
    const float4* __restrict__ kp = kv + i;
    float4*       __restrict__ op = out + i;

    float4 S = make_float4(0.f, 0.f, 0.f, 0.f);

    float4 qa[4], ka[4], qb[4], kb[4];

    // prologue: prefetch group 0 (t = 0..3)
    #pragma unroll
    for (int j = 0; j < 4; ++j) {
        ka[j] = kp[(size_t)j * CH4];
        qa[j] = qp[(size_t)j * CH4];
    }

    for (int g = 0; g < T_DIM / 4; ++g) {
        // prefetch next group while current group's regs are consumed
        if (g + 1 < T_DIM / 4) {
            const int tb = (g + 1) * 4;
            #pragma unroll
            for (int j = 0; j < 4; ++j) {
                kb[j] = kp[(size_t)(tb + j) * CH4];
                qb[j] = qp[(size_t)(tb + j) * CH4];
            }
        }
        // compute current group
        #pragma unroll
        for (int j = 0; j < 4; ++j) {
            S.x = fmaf(d.x, S.x, omd.x * ka[j].x);
            S.y = fmaf(d.y, S.y, omd.y * ka[j].y);
            S.z = fmaf(d.z, S.z, omd.z * ka[j].z);
            S.w = fmaf(d.w, S.w, omd.w * ka[j].w);
            float4 o;
            o.x = qa[j].x * S.x;
            o.y = qa[j].y * S.y;
            o.z = qa[j].z * S.z;
            o.w = qa[j].w * S.w;
            op[(size_t)(g * 4 + j) * CH4] = o;
        }
        // rotate buffers (register-renamed away by the compiler)
        #pragma unroll
        for (int j = 0; j < 4; ++j) { ka[j] = kb[j]; qa[j] = qb[j]; }
    }
}

extern "C" void kernel_launch(void* const* d_in, const int* in_sizes, int n_in,
                              void* d_out, int out_size, void* d_ws, size_t ws_size,
                              hipStream_t stream) {
    const float4* q     = (const float4*)d_in[0];
    const float4* kv    = (const float4*)d_in[1];
    const float*  decay = (const float*)d_in[2];
    float4* out = (float4*)d_out;

    const int threads = 64;
    const int blocks  = CH4 / threads;  // 800
    sss_scan_v4<<<blocks, threads, 0, stream>>>(q, kv, decay, out);
}